// Round 20
// baseline (299.870 us; speedup 1.0000x reference)
//
#include <hip/hip_runtime.h>
#include <hip/hip_bf16.h>

// TriangleMultiplicativeModule (ingoing) — B=1, N=512, D=H=128
// R20 = R19 (passed, 299us) + ONE delta: k_lnout issues its 32 strided mid
//      loads BEFORE the og-GEMM (thread-private reorder; latency hides under
//      32 MFMAs). Og layout/order otherwise byte-identical to R19.

#define NSEQ 512
#define NN 262144        // 512*512
#define PL 262400        // padded plane stride (NN + 256)
#define DMODEL 128

typedef __attribute__((ext_vector_type(8))) short short8;
typedef __attribute__((ext_vector_type(4))) float f32x4;

__device__ __forceinline__ unsigned short f2b(float f) {
    __hip_bfloat16 h = __float2bfloat16(f);
    return *reinterpret_cast<unsigned short*>(&h);
}
__device__ __forceinline__ float b2f(unsigned short u) {
    __hip_bfloat16 h;
    *reinterpret_cast<unsigned short*>(&h) = u;
    return __bfloat162float(h);
}
// hardware packed cvt: lo -> bits[15:0], hi -> bits[31:16]
__device__ __forceinline__ unsigned int cvt_pk_bf16(float lo, float hi) {
    unsigned int r;
    asm("v_cvt_pk_bf16_f32 %0, %1, %2" : "=v"(r) : "v"(lo), "v"(hi));
    return r;
}
// 4-VALU sigmoid: rcp(1 + exp2(-x*log2e)); inf/0 limits correct
__device__ __forceinline__ float sigfast(float x) {
    return __builtin_amdgcn_rcpf(1.f + __builtin_amdgcn_exp2f(x * -1.44269504f));
}
// async global->LDS, 16B per lane; LDS dest = wave-uniform base + lane*16
__device__ __forceinline__ void gload_lds16(const void* g, void* l) {
    __builtin_amdgcn_global_load_lds(
        (const __attribute__((address_space(1))) void*)g,
        (__attribute__((address_space(3))) void*)l, 16, 0, 0);
}

// ---------------------------------------------------------------------------
// All 6 weight transposes in one launch: w[k][h] fp32 -> wt[mat][h][k] bf16
// ---------------------------------------------------------------------------
__global__ __launch_bounds__(256) void k_wt_all(
    const float* __restrict__ w0, const float* __restrict__ w1,
    const float* __restrict__ w2, const float* __restrict__ w3,
    const float* __restrict__ w4, const float* __restrict__ w5,
    unsigned short* __restrict__ wt) {
    int bid = blockIdx.x;
    int mat = bid >> 6;
    const float* w = (mat == 0) ? w0 : (mat == 1) ? w1 : (mat == 2) ? w2
                   : (mat == 3) ? w3 : (mat == 4) ? w4 : w5;
    int idx = (bid & 63) * 256 + threadIdx.x;   // 0..16383
    int d = idx >> 7, h = idx & 127;
    wt[mat * 16384 + h * 128 + d] = f2b(w[idx]);
}

// ---------------------------------------------------------------------------
// LN1 streaming: 2 rows per wave (32 lanes each), float4/lane in, cvt_pk out.
// ---------------------------------------------------------------------------
__global__ __launch_bounds__(256) void k_ln1(const float* __restrict__ x,
                                             const float* __restrict__ sc,
                                             const float* __restrict__ bi,
                                             unsigned short* __restrict__ xn) {
    int t = threadIdx.x;
    int l = t & 31;
    size_t row = (size_t)blockIdx.x * 8 + (t >> 5);
    float4 v = *(const float4*)(x + row * DMODEL + l * 4);
    float s  = v.x + v.y + v.z + v.w;
    float sq = v.x * v.x + v.y * v.y + v.z * v.z + v.w * v.w;
    #pragma unroll
    for (int m = 1; m < 32; m <<= 1) {   // stays within each 32-lane half
        s  += __shfl_xor(s, m);
        sq += __shfl_xor(sq, m);
    }
    float mean = s * (1.f / 128.f);
    float var  = sq * (1.f / 128.f) - mean * mean;
    float inv  = rsqrtf(var + 1e-6f);
    float4 scv = *(const float4*)(sc + l * 4);
    float4 biv = *(const float4*)(bi + l * 4);
    uint2 pk;
    pk.x = cvt_pk_bf16((v.x - mean) * inv * scv.x + biv.x,
                       (v.y - mean) * inv * scv.y + biv.y);
    pk.y = cvt_pk_bf16((v.z - mean) * inv * scv.z + biv.z,
                       (v.w - mean) * inv * scv.w + biv.w);
    *(uint2*)(xn + row * DMODEL + l * 4) = pk;
}

// ---------------------------------------------------------------------------
// Projections (og removed). Block (a0,b): A-tile staged once in padded LDS
// (1 barrier); B-fragments direct global->VGPR (L2-hot, dbuf). 4 GEMMs,
// 2 fused epilogues (bias+mask+sigmoid gate), uint2 stores.
// ---------------------------------------------------------------------------
__global__ __launch_bounds__(256, 2) void k_proj(
    const unsigned short* __restrict__ xn,
    const float* __restrict__ src_mask,
    const unsigned short* __restrict__ wt,  // wl,wlg,wr,wrg (16384 each)
    const float* __restrict__ bl,  const float* __restrict__ blg,
    const float* __restrict__ br,  const float* __restrict__ brg,
    unsigned short* __restrict__ left_t,
    unsigned short* __restrict__ right_t) {
    __shared__ __align__(16) unsigned short As[64 * 136];
    const int t = threadIdx.x;
    const int lane = t & 63;
    const int wv = t >> 6;
    const int a0 = blockIdx.x * 64;
    const int b  = blockIdx.y;
    const int n0 = wv * 32;

    short8 bfA[2][4], bfB[2][4];
    auto loadB = [&](short8 (&dst)[2][4], int mat) {
        const unsigned short* base = wt + mat * 16384 + (lane >> 4) * 8;
        #pragma unroll
        for (int nf = 0; nf < 2; ++nf)
            #pragma unroll
            for (int kc = 0; kc < 4; ++kc)
                dst[nf][kc] = *(const short8*)(
                    base + (n0 + nf * 16 + (lane & 15)) * 128 + kc * 32);
    };
    loadB(bfA, 0);
    loadB(bfB, 1);

    #pragma unroll
    for (int it = 0; it < 4; ++it) {
        int idx = it * 256 + t;
        int row = idx >> 4, c = idx & 15;
        *(short8*)(&As[row * 136 + c * 8]) =
            *(const short8*)(xn + ((size_t)(a0 + row) * NSEQ + b) * DMODEL + c * 8);
    }
    __syncthreads();

    short8 af[4][4];   // [mf][kc]
    #pragma unroll
    for (int mf = 0; mf < 4; ++mf)
        #pragma unroll
        for (int kc = 0; kc < 4; ++kc)
            af[mf][kc] = *(const short8*)(
                &As[(mf * 16 + (lane & 15)) * 136 + kc * 32 + (lane >> 4) * 8]);

    f32x4 acc0[4][2], acc1[4][2];
    float smb = src_mask[b];

    auto mmat = [&](f32x4 (&acc)[4][2], short8 (&bf)[2][4]) {
        #pragma unroll
        for (int mf = 0; mf < 4; ++mf)
            #pragma unroll
            for (int nf = 0; nf < 2; ++nf)
                acc[mf][nf] = f32x4{0.f, 0.f, 0.f, 0.f};
        #pragma unroll
        for (int kc = 0; kc < 4; ++kc)
            #pragma unroll
            for (int mf = 0; mf < 4; ++mf)
                #pragma unroll
                for (int nf = 0; nf < 2; ++nf)
                    acc[mf][nf] = __builtin_amdgcn_mfma_f32_16x16x32_bf16(
                        af[mf][kc], bf[nf][kc], acc[mf][nf], 0, 0, 0);
    };
    auto epi_pair = [&](const float* b1, const float* b2, unsigned short* dst) {
        float mkv[16];
        #pragma unroll
        for (int mf = 0; mf < 4; ++mf)
            #pragma unroll
            for (int j = 0; j < 4; ++j)
                mkv[mf * 4 + j] =
                    src_mask[a0 + mf * 16 + ((lane >> 4) << 2) + j] * smb;
        #pragma unroll
        for (int nf = 0; nf < 2; ++nf) {
            int h = n0 + nf * 16 + (lane & 15);
            float b1v = b1[h], b2v = b2[h];
            #pragma unroll
            for (int mf = 0; mf < 4; ++mf) {
                int abase = a0 + mf * 16 + ((lane >> 4) << 2);
                float o_[4];
                #pragma unroll
                for (int j = 0; j < 4; ++j) {
                    float pv = acc0[mf][nf][j] + b1v;
                    float gv = acc1[mf][nf][j] + b2v;
                    o_[j] = pv * mkv[mf * 4 + j] * sigfast(gv);
                }
                uint2 pk;
                pk.x = cvt_pk_bf16(o_[0], o_[1]);
                pk.y = cvt_pk_bf16(o_[2], o_[3]);
                *(uint2*)(dst + (size_t)h * PL + (size_t)b * NSEQ + abase) = pk;
            }
        }
    };

    // order: 0=wl(acc0) 1=wlg(acc1) -> left; 2=wr 3=wrg -> right
    mmat(acc0, bfA);
    loadB(bfA, 2);
    mmat(acc1, bfB);
    loadB(bfB, 3);
    epi_pair(bl, blg, left_t);
    mmat(acc0, bfA);
    mmat(acc1, bfB);
    epi_pair(br, brg, right_t);
}

// ---------------------------------------------------------------------------
// Einsum: per d-plane GEMM C[i][j] = sum_k A[i][k]*B[j][k].
// 128x128 tile, BK=32, global_load_lds width-16 staging (linear LDS, stride
// 32 shorts), double-buffered, ONE barrier/iter; loads fly under MFMAs.
// ---------------------------------------------------------------------------
__global__ __launch_bounds__(256) void k_einsum(
    const unsigned short* __restrict__ lt,
    const unsigned short* __restrict__ rt,
    unsigned short* __restrict__ mid) {
    __shared__ __align__(16) unsigned short As[2][128 * 32];
    __shared__ __align__(16) unsigned short Bs[2][128 * 32];
    const int t = threadIdx.x, lane = t & 63, wv = t >> 6;
    const int bid = blockIdx.x;
    const int xcd = bid & 7, slot = bid >> 3;
    const int d = xcd * 16 + (slot >> 4);
    const int tile = slot & 15;
    const int i0 = (tile >> 2) * 128, j0 = (tile & 3) * 128;
    const int m0 = (wv >> 1) * 64, n0 = (wv & 1) * 64;
    const unsigned short* Ag = lt + (size_t)d * PL;
    const unsigned short* Bg = rt + (size_t)d * PL;

    auto stage = [&](int buf, int k0) {
        #pragma unroll
        for (int r = 0; r < 2; ++r) {
            int c = r * 256 + wv * 64 + lane;
            int row = c >> 2, sub = c & 3;
            gload_lds16(Ag + (size_t)(i0 + row) * NSEQ + k0 + sub * 8,
                        &As[buf][(r * 256 + wv * 64) * 8]);
            gload_lds16(Bg + (size_t)(j0 + row) * NSEQ + k0 + sub * 8,
                        &Bs[buf][(r * 256 + wv * 64) * 8]);
        }
    };

    f32x4 acc[4][4];
    #pragma unroll
    for (int mf = 0; mf < 4; ++mf)
        #pragma unroll
        for (int nf = 0; nf < 4; ++nf)
            acc[mf][nf] = f32x4{0.f, 0.f, 0.f, 0.f};

    stage(0, 0);
    int cur = 0;
    const int ko = (lane >> 4) * 8;
    for (int it = 0; it < 16; ++it) {
        __syncthreads();                        // drains vmcnt -> buf[cur] ready
        if (it < 15) stage(cur ^ 1, (it + 1) * 32);  // in flight under MFMAs
        short8 af[4], bf[4];
        #pragma unroll
        for (int mf = 0; mf < 4; ++mf)
            af[mf] = *(const short8*)(&As[cur][(m0 + mf * 16 + (lane & 15)) * 32 + ko]);
        #pragma unroll
        for (int nf = 0; nf < 4; ++nf)
            bf[nf] = *(const short8*)(&Bs[cur][(n0 + nf * 16 + (lane & 15)) * 32 + ko]);
        #pragma unroll
        for (int mf = 0; mf < 4; ++mf)
            #pragma unroll
            for (int nf = 0; nf < 4; ++nf)
                acc[mf][nf] = __builtin_amdgcn_mfma_f32_16x16x32_bf16(
                    af[mf], bf[nf], acc[mf][nf], 0, 0, 0);
        cur ^= 1;
    }
    unsigned short* out = mid + (size_t)d * PL;
    #pragma unroll
    for (int mf = 0; mf < 4; ++mf) {
        int rbase = i0 + m0 + mf * 16 + ((lane >> 4) << 2);
        #pragma unroll
        for (int nf = 0; nf < 4; ++nf) {
            int col = j0 + n0 + nf * 16 + (lane & 15);
            #pragma unroll
            for (int j = 0; j < 4; ++j)
                out[(size_t)(rbase + j) * NSEQ + col] = f2b(acc[mf][nf][j]);
        }
    }
}

// ---------------------------------------------------------------------------
// Fused og-recompute + LN2*gate + output projection (R19 structure; mid
// loads issued FIRST so their latency hides under the og-GEMM).
// Block = 64 positions. LDS 36.4KB.
// ---------------------------------------------------------------------------
__global__ __launch_bounds__(256) void k_lnout(
    const unsigned short* __restrict__ mid,
    const unsigned short* __restrict__ xn,
    const unsigned short* __restrict__ wg,   // wog^T [h][k]
    const float* __restrict__ bog,
    const float* __restrict__ sc, const float* __restrict__ bi,
    const unsigned short* __restrict__ wt_o, // wo^T [n][k]
    const float* __restrict__ bo,
    float* __restrict__ out) {
    __shared__ __align__(16) unsigned short As[64 * 136];   // 17408 B
    __shared__ __align__(16) unsigned short Og[64 * 132];   // 16896 B, [row][h]
    __shared__ float2 st[4][64];                            // 2048 B
    const int t = threadIdx.x, lane = t & 63, wv = t >> 6;
    const size_t p0 = (size_t)blockIdx.x * 64;
    const size_t p = p0 + lane;
    const int d0 = wv * 32;

    // issue mid reads FIRST (thread-private; latency hides under og-GEMM)
    unsigned short v16[32];
    #pragma unroll
    for (int e = 0; e < 32; ++e)
        v16[e] = mid[(size_t)(d0 + e) * PL + p];

    // og-GEMM: ga[mf][nf] = xn[p-rows] @ wog^T[d0-slice]
    f32x4 ga[4][2];
    #pragma unroll
    for (int mf = 0; mf < 4; ++mf)
        #pragma unroll
        for (int nf = 0; nf < 2; ++nf)
            ga[mf][nf] = f32x4{0.f, 0.f, 0.f, 0.f};
    #pragma unroll
    for (int kc = 0; kc < 4; ++kc) {
        short8 af[4], gb[2];
        #pragma unroll
        for (int mf = 0; mf < 4; ++mf)
            af[mf] = *(const short8*)(
                xn + (p0 + mf * 16 + (lane & 15)) * DMODEL + kc * 32 + (lane >> 4) * 8);
        #pragma unroll
        for (int nf = 0; nf < 2; ++nf)
            gb[nf] = *(const short8*)(
                wg + (d0 + nf * 16 + (lane & 15)) * 128 + kc * 32 + (lane >> 4) * 8);
        #pragma unroll
        for (int mf = 0; mf < 4; ++mf)
            #pragma unroll
            for (int nf = 0; nf < 2; ++nf)
                ga[mf][nf] = __builtin_amdgcn_mfma_f32_16x16x32_bf16(
                    af[mf], gb[nf], ga[mf][nf], 0, 0, 0);
    }

    // stats from v16 (loads already in flight / returned)
    float s = 0.f, sq = 0.f;
    #pragma unroll
    for (int e = 0; e < 32; ++e) {
        float f = b2f(v16[e]);
        s += f; sq += f * f;
    }

    // og epilogue: sigmoid -> Og[row][h] (stride 132)  [R19-identical]
    #pragma unroll
    for (int nf = 0; nf < 2; ++nf) {
        int hc = d0 + nf * 16 + (lane & 15);
        float bv = bog[hc];
        #pragma unroll
        for (int mf = 0; mf < 4; ++mf) {
            int r = mf * 16 + ((lane >> 4) << 2);
            #pragma unroll
            for (int j = 0; j < 4; ++j)
                Og[(r + j) * 132 + hc] = f2b(sigfast(ga[mf][nf][j] + bv));
        }
    }

    st[wv][lane] = float2{s, sq};
    __syncthreads();
    float2 s0 = st[0][lane], s1 = st[1][lane], s2 = st[2][lane], s3 = st[3][lane];
    float S = s0.x + s1.x + s2.x + s3.x;
    float Q = s0.y + s1.y + s2.y + s3.y;
    float mean = S * (1.f / 128.f);
    float inv  = rsqrtf(Q * (1.f / 128.f) - mean * mean + 1e-6f);

    // normalize * og -> As[lane][d0..d0+31]
    #pragma unroll
    for (int c = 0; c < 4; ++c) {
        short8 ov = *(const short8*)(&Og[lane * 132 + d0 + c * 8]);
        float y[8];
        #pragma unroll
        for (int e = 0; e < 8; ++e) {
            int dd = d0 + c * 8 + e;
            float v = b2f(v16[c * 8 + e]);
            y[e] = ((v - mean) * inv * sc[dd] + bi[dd]) * b2f((unsigned short)ov[e]);
        }
        uint4 pk;
        pk.x = cvt_pk_bf16(y[0], y[1]);
        pk.y = cvt_pk_bf16(y[2], y[3]);
        pk.z = cvt_pk_bf16(y[4], y[5]);
        pk.w = cvt_pk_bf16(y[6], y[7]);
        *(uint4*)(&As[lane * 136 + d0 + c * 8]) = pk;
    }
    __syncthreads();

    // final GEMM: out[64 x 128] = As @ wo^T(+bo); B-frags direct from global
    const int n0 = wv * 32;
    short8 bf[2][4];
    #pragma unroll
    for (int nf = 0; nf < 2; ++nf)
        #pragma unroll
        for (int kc = 0; kc < 4; ++kc)
            bf[nf][kc] = *(const short8*)(
                wt_o + (n0 + nf * 16 + (lane & 15)) * 128 + kc * 32 + (lane >> 4) * 8);
    f32x4 acc[4][2];
    #pragma unroll
    for (int mf = 0; mf < 4; ++mf)
        #pragma unroll
        for (int nf = 0; nf < 2; ++nf)
            acc[mf][nf] = f32x4{0.f, 0.f, 0.f, 0.f};
    #pragma unroll
    for (int kc = 0; kc < 4; ++kc) {
        int ko = kc * 32 + (lane >> 4) * 8;
        short8 af[4];
        #pragma unroll
        for (int mf = 0; mf < 4; ++mf)
            af[mf] = *(const short8*)(&As[(mf * 16 + (lane & 15)) * 136 + ko]);
        #pragma unroll
        for (int mf = 0; mf < 4; ++mf)
            #pragma unroll
            for (int nf = 0; nf < 2; ++nf)
                acc[mf][nf] = __builtin_amdgcn_mfma_f32_16x16x32_bf16(
                    af[mf], bf[nf][kc], acc[mf][nf], 0, 0, 0);
    }
    #pragma unroll
    for (int nf = 0; nf < 2; ++nf) {
        int n = n0 + nf * 16 + (lane & 15);
        float bv = bo[n];
        #pragma unroll
        for (int mf = 0; mf < 4; ++mf) {
            int rb = mf * 16 + ((lane >> 4) << 2);
            #pragma unroll
            for (int j = 0; j < 4; ++j)
                out[(p0 + rb + j) * DMODEL + n] = acc[mf][nf][j] + bv;
        }
    }
}

// ---------------------------------------------------------------------------
extern "C" void kernel_launch(void* const* d_in, const int* in_sizes, int n_in,
                              void* d_out, int out_size, void* d_ws, size_t ws_size,
                              hipStream_t stream) {
    const float* x    = (const float*)d_in[0];
    const float* sm   = (const float*)d_in[1];
    const float* ln1s = (const float*)d_in[2];
    const float* ln1b = (const float*)d_in[3];
    const float* wl   = (const float*)d_in[4];
    const float* bl   = (const float*)d_in[5];
    const float* wr   = (const float*)d_in[6];
    const float* br   = (const float*)d_in[7];
    const float* wlg  = (const float*)d_in[8];
    const float* blg  = (const float*)d_in[9];
    const float* wrg  = (const float*)d_in[10];
    const float* brg  = (const float*)d_in[11];
    const float* wog  = (const float*)d_in[12];
    const float* bog  = (const float*)d_in[13];
    const float* ln2s = (const float*)d_in[14];
    const float* ln2b = (const float*)d_in[15];
    const float* wo   = (const float*)d_in[16];
    const float* bo   = (const float*)d_in[17];
    float* out = (float*)d_out;

    // workspace: wt | xn(64MB) | lt | rt (padded 64.06MB) | mid
    char* ws = (char*)d_ws;
    const size_t SZ_XN = 67108864ull;           // 64 MB
    const size_t SZ_PL = (size_t)PL * 128 * 2;  // 67,174,400 B
    unsigned short* wt  = (unsigned short*)ws;
    unsigned short* xn  = (unsigned short*)(ws + 196608);
    unsigned short* lt  = (unsigned short*)(ws + 196608 + SZ_XN);
    unsigned short* rt  = (unsigned short*)(ws + 196608 + SZ_XN + SZ_PL);
    unsigned short* mid = (unsigned short*)(ws + 196608 + SZ_XN + 2 * SZ_PL);

    k_wt_all<<<384, 256, 0, stream>>>(wl, wlg, wr, wrg, wog, wo, wt);
    k_ln1<<<32768, 256, 0, stream>>>(x, ln1s, ln1b, xn);
    k_proj<<<dim3(8, 512), 256, 0, stream>>>(xn, sm, wt,
                                             bl, blg, br, brg, lt, rt);
    k_einsum<<<2048, 256, 0, stream>>>(lt, rt, mid);
    k_lnout<<<4096, 256, 0, stream>>>(mid, xn, wt + 4 * 16384, bog,
                                      ln2s, ln2b, wt + 5 * 16384, bo, out);
}

// Round 21
// 295.721 us; speedup vs baseline: 1.0140x; 1.0140x over previous
//
#include <hip/hip_runtime.h>
#include <hip/hip_bf16.h>

// TriangleMultiplicativeModule (ingoing) — B=1, N=512, D=H=128
// R21 FINAL = R16/R14/R12 best-measured config (295.8/296.3 us):
//   k_ln1 (streaming LN + bf16 cast), k_proj (5 GEMMs, A in LDS once,
//   B direct->VGPR dbuf, fused mask/sigmoid epilogues, og via LDS),
//   k_einsum (gload_lds width-16 dbuf, 1 barrier/iter, XCD plane swizzle),
//   k_lnout (fused LN2*gate + out-proj reading materialized og).
// og-recompute family (R17-R20) measured consistently ~3us slower; k_proj
// structure floored at ~136us over 8 variants; reverting to verified best.

#define NSEQ 512
#define NN 262144        // 512*512
#define PL 262400        // padded plane stride (NN + 256)
#define DMODEL 128

typedef __attribute__((ext_vector_type(8))) short short8;
typedef __attribute__((ext_vector_type(4))) float f32x4;

__device__ __forceinline__ unsigned short f2b(float f) {
    __hip_bfloat16 h = __float2bfloat16(f);
    return *reinterpret_cast<unsigned short*>(&h);
}
__device__ __forceinline__ float b2f(unsigned short u) {
    __hip_bfloat16 h;
    *reinterpret_cast<unsigned short*>(&h) = u;
    return __bfloat162float(h);
}
// hardware packed cvt: lo -> bits[15:0], hi -> bits[31:16]
__device__ __forceinline__ unsigned int cvt_pk_bf16(float lo, float hi) {
    unsigned int r;
    asm("v_cvt_pk_bf16_f32 %0, %1, %2" : "=v"(r) : "v"(lo), "v"(hi));
    return r;
}
// 4-VALU sigmoid: rcp(1 + exp2(-x*log2e)); inf/0 limits correct
__device__ __forceinline__ float sigfast(float x) {
    return __builtin_amdgcn_rcpf(1.f + __builtin_amdgcn_exp2f(x * -1.44269504f));
}
// async global->LDS, 16B per lane; LDS dest = wave-uniform base + lane*16
__device__ __forceinline__ void gload_lds16(const void* g, void* l) {
    __builtin_amdgcn_global_load_lds(
        (const __attribute__((address_space(1))) void*)g,
        (__attribute__((address_space(3))) void*)l, 16, 0, 0);
}

// ---------------------------------------------------------------------------
// All 6 weight transposes in one launch: w[k][h] fp32 -> wt[mat][h][k] bf16
// ---------------------------------------------------------------------------
__global__ __launch_bounds__(256) void k_wt_all(
    const float* __restrict__ w0, const float* __restrict__ w1,
    const float* __restrict__ w2, const float* __restrict__ w3,
    const float* __restrict__ w4, const float* __restrict__ w5,
    unsigned short* __restrict__ wt) {
    int bid = blockIdx.x;
    int mat = bid >> 6;
    const float* w = (mat == 0) ? w0 : (mat == 1) ? w1 : (mat == 2) ? w2
                   : (mat == 3) ? w3 : (mat == 4) ? w4 : w5;
    int idx = (bid & 63) * 256 + threadIdx.x;   // 0..16383
    int d = idx >> 7, h = idx & 127;
    wt[mat * 16384 + h * 128 + d] = f2b(w[idx]);
}

// ---------------------------------------------------------------------------
// LN1 streaming: 2 rows per wave (32 lanes each), float4/lane in, cvt_pk out.
// ---------------------------------------------------------------------------
__global__ __launch_bounds__(256) void k_ln1(const float* __restrict__ x,
                                             const float* __restrict__ sc,
                                             const float* __restrict__ bi,
                                             unsigned short* __restrict__ xn) {
    int t = threadIdx.x;
    int l = t & 31;
    size_t row = (size_t)blockIdx.x * 8 + (t >> 5);
    float4 v = *(const float4*)(x + row * DMODEL + l * 4);
    float s  = v.x + v.y + v.z + v.w;
    float sq = v.x * v.x + v.y * v.y + v.z * v.z + v.w * v.w;
    #pragma unroll
    for (int m = 1; m < 32; m <<= 1) {   // stays within each 32-lane half
        s  += __shfl_xor(s, m);
        sq += __shfl_xor(sq, m);
    }
    float mean = s * (1.f / 128.f);
    float var  = sq * (1.f / 128.f) - mean * mean;
    float inv  = rsqrtf(var + 1e-6f);
    float4 scv = *(const float4*)(sc + l * 4);
    float4 biv = *(const float4*)(bi + l * 4);
    uint2 pk;
    pk.x = cvt_pk_bf16((v.x - mean) * inv * scv.x + biv.x,
                       (v.y - mean) * inv * scv.y + biv.y);
    pk.y = cvt_pk_bf16((v.z - mean) * inv * scv.z + biv.z,
                       (v.w - mean) * inv * scv.w + biv.w);
    *(uint2*)(xn + row * DMODEL + l * 4) = pk;
}

// ---------------------------------------------------------------------------
// Projections. Block (a0,b): A-tile staged once in padded LDS (1 barrier);
// B-fragments direct global->VGPR (L2-hot, dbuf). Cheap epilogues (cvt_pk,
// sigfast, hoisted mask). og via LDS for full-line stores.
// ---------------------------------------------------------------------------
__global__ __launch_bounds__(256, 2) void k_proj(
    const unsigned short* __restrict__ xn,
    const float* __restrict__ src_mask,
    const unsigned short* __restrict__ wt,  // wl,wlg,wr,wrg,wog (16384 each)
    const float* __restrict__ bl,  const float* __restrict__ blg,
    const float* __restrict__ br,  const float* __restrict__ brg,
    const float* __restrict__ bog,
    unsigned short* __restrict__ left_t,
    unsigned short* __restrict__ right_t,
    unsigned short* __restrict__ og) {
    __shared__ __align__(16) unsigned short As[64 * 136];
    const int t = threadIdx.x;
    const int lane = t & 63;
    const int wv = t >> 6;
    const int a0 = blockIdx.x * 64;
    const int b  = blockIdx.y;
    const int n0 = wv * 32;

    short8 bfA[2][4], bfB[2][4];
    auto loadB = [&](short8 (&dst)[2][4], int mat) {
        const unsigned short* base = wt + mat * 16384 + (lane >> 4) * 8;
        #pragma unroll
        for (int nf = 0; nf < 2; ++nf)
            #pragma unroll
            for (int kc = 0; kc < 4; ++kc)
                dst[nf][kc] = *(const short8*)(
                    base + (n0 + nf * 16 + (lane & 15)) * 128 + kc * 32);
    };
    loadB(bfA, 0);
    loadB(bfB, 1);

    #pragma unroll
    for (int it = 0; it < 4; ++it) {
        int idx = it * 256 + t;
        int row = idx >> 4, c = idx & 15;
        *(short8*)(&As[row * 136 + c * 8]) =
            *(const short8*)(xn + ((size_t)(a0 + row) * NSEQ + b) * DMODEL + c * 8);
    }
    __syncthreads();

    short8 af[4][4];   // [mf][kc]
    #pragma unroll
    for (int mf = 0; mf < 4; ++mf)
        #pragma unroll
        for (int kc = 0; kc < 4; ++kc)
            af[mf][kc] = *(const short8*)(
                &As[(mf * 16 + (lane & 15)) * 136 + kc * 32 + (lane >> 4) * 8]);

    f32x4 acc0[4][2], acc1[4][2];
    float smb = src_mask[b];

    auto mmat = [&](f32x4 (&acc)[4][2], short8 (&bf)[2][4]) {
        #pragma unroll
        for (int mf = 0; mf < 4; ++mf)
            #pragma unroll
            for (int nf = 0; nf < 2; ++nf)
                acc[mf][nf] = f32x4{0.f, 0.f, 0.f, 0.f};
        #pragma unroll
        for (int kc = 0; kc < 4; ++kc)
            #pragma unroll
            for (int mf = 0; mf < 4; ++mf)
                #pragma unroll
                for (int nf = 0; nf < 2; ++nf)
                    acc[mf][nf] = __builtin_amdgcn_mfma_f32_16x16x32_bf16(
                        af[mf][kc], bf[nf][kc], acc[mf][nf], 0, 0, 0);
    };
    auto epi_pair = [&](const float* b1, const float* b2, unsigned short* dst) {
        float mkv[16];
        #pragma unroll
        for (int mf = 0; mf < 4; ++mf)
            #pragma unroll
            for (int j = 0; j < 4; ++j)
                mkv[mf * 4 + j] =
                    src_mask[a0 + mf * 16 + ((lane >> 4) << 2) + j] * smb;
        #pragma unroll
        for (int nf = 0; nf < 2; ++nf) {
            int h = n0 + nf * 16 + (lane & 15);
            float b1v = b1[h], b2v = b2[h];
            #pragma unroll
            for (int mf = 0; mf < 4; ++mf) {
                int abase = a0 + mf * 16 + ((lane >> 4) << 2);
                float o_[4];
                #pragma unroll
                for (int j = 0; j < 4; ++j) {
                    float pv = acc0[mf][nf][j] + b1v;
                    float gv = acc1[mf][nf][j] + b2v;
                    o_[j] = pv * mkv[mf * 4 + j] * sigfast(gv);
                }
                uint2 pk;
                pk.x = cvt_pk_bf16(o_[0], o_[1]);
                pk.y = cvt_pk_bf16(o_[2], o_[3]);
                *(uint2*)(dst + (size_t)h * PL + (size_t)b * NSEQ + abase) = pk;
            }
        }
    };

    // order: 0=wl(acc0) 1=wlg(acc1) -> left; 2=wr 3=wrg -> right; 4=wog
    mmat(acc0, bfA);
    loadB(bfA, 2);
    mmat(acc1, bfB);
    loadB(bfB, 3);
    epi_pair(bl, blg, left_t);
    mmat(acc0, bfA);
    loadB(bfA, 4);
    mmat(acc1, bfB);
    epi_pair(br, brg, right_t);
    mmat(acc0, bfA);

    __syncthreads();
    #pragma unroll
    for (int nf = 0; nf < 2; ++nf) {
        int h = n0 + nf * 16 + (lane & 15);
        float bv = bog[h];
        #pragma unroll
        for (int mf = 0; mf < 4; ++mf) {
            int rloc = mf * 16 + ((lane >> 4) << 2);
            #pragma unroll
            for (int j = 0; j < 4; ++j)
                As[(rloc + j) * 136 + h] = f2b(sigfast(acc0[mf][nf][j] + bv));
        }
    }
    __syncthreads();
    #pragma unroll
    for (int it = 0; it < 4; ++it) {
        int idx = it * 256 + t;
        int row = idx >> 4, c = idx & 15;
        *(short8*)(og + ((size_t)(a0 + row) * NSEQ + b) * DMODEL + c * 8) =
            *(const short8*)(&As[row * 136 + c * 8]);
    }
}

// ---------------------------------------------------------------------------
// Einsum: per d-plane GEMM C[i][j] = sum_k A[i][k]*B[j][k].
// 128x128 tile, BK=32, global_load_lds width-16 staging (linear LDS, stride
// 32 shorts), double-buffered, ONE barrier/iter; loads fly under MFMAs.
// ---------------------------------------------------------------------------
__global__ __launch_bounds__(256) void k_einsum(
    const unsigned short* __restrict__ lt,
    const unsigned short* __restrict__ rt,
    unsigned short* __restrict__ mid) {
    __shared__ __align__(16) unsigned short As[2][128 * 32];
    __shared__ __align__(16) unsigned short Bs[2][128 * 32];
    const int t = threadIdx.x, lane = t & 63, wv = t >> 6;
    const int bid = blockIdx.x;
    const int xcd = bid & 7, slot = bid >> 3;
    const int d = xcd * 16 + (slot >> 4);
    const int tile = slot & 15;
    const int i0 = (tile >> 2) * 128, j0 = (tile & 3) * 128;
    const int m0 = (wv >> 1) * 64, n0 = (wv & 1) * 64;
    const unsigned short* Ag = lt + (size_t)d * PL;
    const unsigned short* Bg = rt + (size_t)d * PL;

    auto stage = [&](int buf, int k0) {
        #pragma unroll
        for (int r = 0; r < 2; ++r) {
            int c = r * 256 + wv * 64 + lane;
            int row = c >> 2, sub = c & 3;
            gload_lds16(Ag + (size_t)(i0 + row) * NSEQ + k0 + sub * 8,
                        &As[buf][(r * 256 + wv * 64) * 8]);
            gload_lds16(Bg + (size_t)(j0 + row) * NSEQ + k0 + sub * 8,
                        &Bs[buf][(r * 256 + wv * 64) * 8]);
        }
    };

    f32x4 acc[4][4];
    #pragma unroll
    for (int mf = 0; mf < 4; ++mf)
        #pragma unroll
        for (int nf = 0; nf < 4; ++nf)
            acc[mf][nf] = f32x4{0.f, 0.f, 0.f, 0.f};

    stage(0, 0);
    int cur = 0;
    const int ko = (lane >> 4) * 8;
    for (int it = 0; it < 16; ++it) {
        __syncthreads();                        // drains vmcnt -> buf[cur] ready
        if (it < 15) stage(cur ^ 1, (it + 1) * 32);  // in flight under MFMAs
        short8 af[4], bf[4];
        #pragma unroll
        for (int mf = 0; mf < 4; ++mf)
            af[mf] = *(const short8*)(&As[cur][(m0 + mf * 16 + (lane & 15)) * 32 + ko]);
        #pragma unroll
        for (int nf = 0; nf < 4; ++nf)
            bf[nf] = *(const short8*)(&Bs[cur][(n0 + nf * 16 + (lane & 15)) * 32 + ko]);
        #pragma unroll
        for (int mf = 0; mf < 4; ++mf)
            #pragma unroll
            for (int nf = 0; nf < 4; ++nf)
                acc[mf][nf] = __builtin_amdgcn_mfma_f32_16x16x32_bf16(
                    af[mf], bf[nf], acc[mf][nf], 0, 0, 0);
        cur ^= 1;
    }
    unsigned short* out = mid + (size_t)d * PL;
    #pragma unroll
    for (int mf = 0; mf < 4; ++mf) {
        int rbase = i0 + m0 + mf * 16 + ((lane >> 4) << 2);
        #pragma unroll
        for (int nf = 0; nf < 4; ++nf) {
            int col = j0 + n0 + nf * 16 + (lane & 15);
            #pragma unroll
            for (int j = 0; j < 4; ++j)
                out[(size_t)(rbase + j) * NSEQ + col] = f2b(acc[mf][nf][j]);
        }
    }
}

// ---------------------------------------------------------------------------
// Fused LN2*gate + output projection. Block = 64 positions, 256 threads.
// Phase 1: wave w reads d-slice [32w,32w+32) of mid for position p0+lane
// (coalesced 128B/wave per plane), 4-wave LDS stats reduce, normalize*og
// -> bf16 A-tile in LDS. Phase 2: GEMM (A 64x128 @ wo) -> fp32 out.
// ---------------------------------------------------------------------------
__global__ __launch_bounds__(256) void k_lnout(
    const unsigned short* __restrict__ mid,
    const unsigned short* __restrict__ og,
    const float* __restrict__ sc, const float* __restrict__ bi,
    const unsigned short* __restrict__ wt_o,
    const float* __restrict__ bo,
    float* __restrict__ out) {
    __shared__ __align__(16) unsigned short As[64 * 136];
    __shared__ __align__(16) unsigned short Bs[128 * 136];
    __shared__ float2 st[4][64];
    const int t = threadIdx.x, lane = t & 63, wv = t >> 6;
    const size_t p0 = (size_t)blockIdx.x * 64;
    const size_t p = p0 + lane;
    const int d0 = wv * 32;

    // stage Bs (wo^T) early — overlaps the strided mid reads
    #pragma unroll
    for (int it = 0; it < 8; ++it) {
        int idx = it * 256 + t;
        int h = idx >> 4, c = idx & 15;
        *(short8*)(&Bs[h * 136 + c * 8]) = *(const short8*)(wt_o + h * 128 + c * 8);
    }

    // read my 32 d-planes for position p
    unsigned short v16[32];
    float s = 0.f, sq = 0.f;
    #pragma unroll
    for (int e = 0; e < 32; ++e) {
        unsigned short u = mid[(size_t)(d0 + e) * PL + p];
        v16[e] = u;
        float f = b2f(u);
        s += f; sq += f * f;
    }
    st[wv][lane] = float2{s, sq};
    __syncthreads();
    float2 s0 = st[0][lane], s1 = st[1][lane], s2 = st[2][lane], s3 = st[3][lane];
    float S = s0.x + s1.x + s2.x + s3.x;
    float Q = s0.y + s1.y + s2.y + s3.y;
    float mean = S * (1.f / 128.f);
    float inv  = rsqrtf(Q * (1.f / 128.f) - mean * mean + 1e-6f);

    // normalize * og -> As[lane][d0..d0+31] (uint4 stores, 272B row stride)
    #pragma unroll
    for (int c = 0; c < 4; ++c) {
        short8 ov = *(const short8*)(og + p * DMODEL + d0 + c * 8);
        float y[8];
        #pragma unroll
        for (int e = 0; e < 8; ++e) {
            int dd = d0 + c * 8 + e;
            float v = b2f(v16[c * 8 + e]);
            y[e] = ((v - mean) * inv * sc[dd] + bi[dd]) * b2f((unsigned short)ov[e]);
        }
        uint4 pk;
        pk.x = cvt_pk_bf16(y[0], y[1]);
        pk.y = cvt_pk_bf16(y[2], y[3]);
        pk.z = cvt_pk_bf16(y[4], y[5]);
        pk.w = cvt_pk_bf16(y[6], y[7]);
        *(uint4*)(&As[lane * 136 + d0 + c * 8]) = pk;
    }
    __syncthreads();

    // GEMM: out[64 x 128] = As @ Bs^T(+bo), wave n-slice 32
    const int n0 = wv * 32;
    f32x4 acc[4][2];
    #pragma unroll
    for (int mf = 0; mf < 4; ++mf)
        #pragma unroll
        for (int nf = 0; nf < 2; ++nf)
            acc[mf][nf] = f32x4{0.f, 0.f, 0.f, 0.f};
    #pragma unroll
    for (int kc = 0; kc < 4; ++kc) {
        int ko = kc * 32 + (lane >> 4) * 8;
        short8 af[4], bf[2];
        #pragma unroll
        for (int mf = 0; mf < 4; ++mf)
            af[mf] = *(const short8*)(&As[(mf * 16 + (lane & 15)) * 136 + ko]);
        #pragma unroll
        for (int nf = 0; nf < 2; ++nf)
            bf[nf] = *(const short8*)(&Bs[(n0 + nf * 16 + (lane & 15)) * 136 + ko]);
        #pragma unroll
        for (int mf = 0; mf < 4; ++mf)
            #pragma unroll
            for (int nf = 0; nf < 2; ++nf)
                acc[mf][nf] = __builtin_amdgcn_mfma_f32_16x16x32_bf16(
                    af[mf], bf[nf], acc[mf][nf], 0, 0, 0);
    }
    #pragma unroll
    for (int nf = 0; nf < 2; ++nf) {
        int n = n0 + nf * 16 + (lane & 15);
        float bv = bo[n];
        #pragma unroll
        for (int mf = 0; mf < 4; ++mf) {
            int rb = mf * 16 + ((lane >> 4) << 2);
            #pragma unroll
            for (int j = 0; j < 4; ++j)
                out[(p0 + rb + j) * DMODEL + n] = acc[mf][nf][j] + bv;
        }
    }
}

// ---------------------------------------------------------------------------
extern "C" void kernel_launch(void* const* d_in, const int* in_sizes, int n_in,
                              void* d_out, int out_size, void* d_ws, size_t ws_size,
                              hipStream_t stream) {
    const float* x    = (const float*)d_in[0];
    const float* sm   = (const float*)d_in[1];
    const float* ln1s = (const float*)d_in[2];
    const float* ln1b = (const float*)d_in[3];
    const float* wl   = (const float*)d_in[4];
    const float* bl   = (const float*)d_in[5];
    const float* wr   = (const float*)d_in[6];
    const float* br   = (const float*)d_in[7];
    const float* wlg  = (const float*)d_in[8];
    const float* blg  = (const float*)d_in[9];
    const float* wrg  = (const float*)d_in[10];
    const float* brg  = (const float*)d_in[11];
    const float* wog  = (const float*)d_in[12];
    const float* bog  = (const float*)d_in[13];
    const float* ln2s = (const float*)d_in[14];
    const float* ln2b = (const float*)d_in[15];
    const float* wo   = (const float*)d_in[16];
    const float* bo   = (const float*)d_in[17];
    float* out = (float*)d_out;

    // workspace: wt | xn(64MB) | lt | rt (padded 64.06MB) | og(64MB) | mid
    char* ws = (char*)d_ws;
    const size_t SZ_XN = 67108864ull;           // 64 MB
    const size_t SZ_PL = (size_t)PL * 128 * 2;  // 67,174,400 B
    unsigned short* wt  = (unsigned short*)ws;
    unsigned short* xn  = (unsigned short*)(ws + 196608);
    unsigned short* lt  = (unsigned short*)(ws + 196608 + SZ_XN);
    unsigned short* rt  = (unsigned short*)(ws + 196608 + SZ_XN + SZ_PL);
    unsigned short* ogb = (unsigned short*)(ws + 196608 + SZ_XN + 2 * SZ_PL);
    unsigned short* mid = (unsigned short*)(ws + 196608 + 2 * SZ_XN + 2 * SZ_PL);

    k_wt_all<<<384, 256, 0, stream>>>(wl, wlg, wr, wrg, wog, wo, wt);
    k_ln1<<<32768, 256, 0, stream>>>(x, ln1s, ln1b, xn);
    k_proj<<<dim3(8, 512), 256, 0, stream>>>(xn, sm, wt,
                                             bl, blg, br, brg, bog, lt, rt, ogb);
    k_einsum<<<2048, 256, 0, stream>>>(lt, rt, mid);
    k_lnout<<<4096, 256, 0, stream>>>(mid, ogb, ln2s, ln2b,
                                      wt + 5 * 16384, bo, out);
}

// Round 22
// 295.690 us; speedup vs baseline: 1.0141x; 1.0001x over previous
//
#include <hip/hip_runtime.h>
#include <hip/hip_bf16.h>

// TriangleMultiplicativeModule (ingoing) — B=1, N=512, D=H=128
// FINAL (verified 295.7/295.8/296.3 us across three runs):
//   k_wt_all: 6 weight transposes+bf16 cast, one launch
//   k_ln1:    streaming LN over D + bf16 cast (5.7 TB/s effective)
//   k_proj:   5 fused projection GEMMs; A-tile in LDS once (1 barrier),
//             B direct global->VGPR dbuf (L2-hot), fused bias/mask/sigmoid
//             epilogues via v_cvt_pk_bf16_f32 + 4-op sigmoid; og via LDS
//   k_einsum: per-d-plane 512^2 GEMM; global_load_lds width-16 staging,
//             double-buffered, 1 barrier/iter, XCD plane-locality swizzle
//   k_lnout:  fused LN2*gate + output projection (one pass over mid)
// Plateau is latency-structural (all pipes <30% busy; 8 k_proj variants,
// occupancy and reorder levers all probed to null/falsification).

#define NSEQ 512
#define NN 262144        // 512*512
#define PL 262400        // padded plane stride (NN + 256)
#define DMODEL 128

typedef __attribute__((ext_vector_type(8))) short short8;
typedef __attribute__((ext_vector_type(4))) float f32x4;

__device__ __forceinline__ unsigned short f2b(float f) {
    __hip_bfloat16 h = __float2bfloat16(f);
    return *reinterpret_cast<unsigned short*>(&h);
}
__device__ __forceinline__ float b2f(unsigned short u) {
    __hip_bfloat16 h;
    *reinterpret_cast<unsigned short*>(&h) = u;
    return __bfloat162float(h);
}
// hardware packed cvt: lo -> bits[15:0], hi -> bits[31:16]
__device__ __forceinline__ unsigned int cvt_pk_bf16(float lo, float hi) {
    unsigned int r;
    asm("v_cvt_pk_bf16_f32 %0, %1, %2" : "=v"(r) : "v"(lo), "v"(hi));
    return r;
}
// 4-VALU sigmoid: rcp(1 + exp2(-x*log2e)); inf/0 limits correct
__device__ __forceinline__ float sigfast(float x) {
    return __builtin_amdgcn_rcpf(1.f + __builtin_amdgcn_exp2f(x * -1.44269504f));
}
// async global->LDS, 16B per lane; LDS dest = wave-uniform base + lane*16
__device__ __forceinline__ void gload_lds16(const void* g, void* l) {
    __builtin_amdgcn_global_load_lds(
        (const __attribute__((address_space(1))) void*)g,
        (__attribute__((address_space(3))) void*)l, 16, 0, 0);
}

// ---------------------------------------------------------------------------
// All 6 weight transposes in one launch: w[k][h] fp32 -> wt[mat][h][k] bf16
// ---------------------------------------------------------------------------
__global__ __launch_bounds__(256) void k_wt_all(
    const float* __restrict__ w0, const float* __restrict__ w1,
    const float* __restrict__ w2, const float* __restrict__ w3,
    const float* __restrict__ w4, const float* __restrict__ w5,
    unsigned short* __restrict__ wt) {
    int bid = blockIdx.x;
    int mat = bid >> 6;
    const float* w = (mat == 0) ? w0 : (mat == 1) ? w1 : (mat == 2) ? w2
                   : (mat == 3) ? w3 : (mat == 4) ? w4 : w5;
    int idx = (bid & 63) * 256 + threadIdx.x;   // 0..16383
    int d = idx >> 7, h = idx & 127;
    wt[mat * 16384 + h * 128 + d] = f2b(w[idx]);
}

// ---------------------------------------------------------------------------
// LN1 streaming: 2 rows per wave (32 lanes each), float4/lane in, cvt_pk out.
// ---------------------------------------------------------------------------
__global__ __launch_bounds__(256) void k_ln1(const float* __restrict__ x,
                                             const float* __restrict__ sc,
                                             const float* __restrict__ bi,
                                             unsigned short* __restrict__ xn) {
    int t = threadIdx.x;
    int l = t & 31;
    size_t row = (size_t)blockIdx.x * 8 + (t >> 5);
    float4 v = *(const float4*)(x + row * DMODEL + l * 4);
    float s  = v.x + v.y + v.z + v.w;
    float sq = v.x * v.x + v.y * v.y + v.z * v.z + v.w * v.w;
    #pragma unroll
    for (int m = 1; m < 32; m <<= 1) {   // stays within each 32-lane half
        s  += __shfl_xor(s, m);
        sq += __shfl_xor(sq, m);
    }
    float mean = s * (1.f / 128.f);
    float var  = sq * (1.f / 128.f) - mean * mean;
    float inv  = rsqrtf(var + 1e-6f);
    float4 scv = *(const float4*)(sc + l * 4);
    float4 biv = *(const float4*)(bi + l * 4);
    uint2 pk;
    pk.x = cvt_pk_bf16((v.x - mean) * inv * scv.x + biv.x,
                       (v.y - mean) * inv * scv.y + biv.y);
    pk.y = cvt_pk_bf16((v.z - mean) * inv * scv.z + biv.z,
                       (v.w - mean) * inv * scv.w + biv.w);
    *(uint2*)(xn + row * DMODEL + l * 4) = pk;
}

// ---------------------------------------------------------------------------
// Projections. Block (a0,b): A-tile staged once in padded LDS (1 barrier);
// B-fragments direct global->VGPR (L2-hot, dbuf). Cheap epilogues (cvt_pk,
// sigfast, hoisted mask). og via LDS for full-line stores.
// ---------------------------------------------------------------------------
__global__ __launch_bounds__(256, 2) void k_proj(
    const unsigned short* __restrict__ xn,
    const float* __restrict__ src_mask,
    const unsigned short* __restrict__ wt,  // wl,wlg,wr,wrg,wog (16384 each)
    const float* __restrict__ bl,  const float* __restrict__ blg,
    const float* __restrict__ br,  const float* __restrict__ brg,
    const float* __restrict__ bog,
    unsigned short* __restrict__ left_t,
    unsigned short* __restrict__ right_t,
    unsigned short* __restrict__ og) {
    __shared__ __align__(16) unsigned short As[64 * 136];
    const int t = threadIdx.x;
    const int lane = t & 63;
    const int wv = t >> 6;
    const int a0 = blockIdx.x * 64;
    const int b  = blockIdx.y;
    const int n0 = wv * 32;

    short8 bfA[2][4], bfB[2][4];
    auto loadB = [&](short8 (&dst)[2][4], int mat) {
        const unsigned short* base = wt + mat * 16384 + (lane >> 4) * 8;
        #pragma unroll
        for (int nf = 0; nf < 2; ++nf)
            #pragma unroll
            for (int kc = 0; kc < 4; ++kc)
                dst[nf][kc] = *(const short8*)(
                    base + (n0 + nf * 16 + (lane & 15)) * 128 + kc * 32);
    };
    loadB(bfA, 0);
    loadB(bfB, 1);

    #pragma unroll
    for (int it = 0; it < 4; ++it) {
        int idx = it * 256 + t;
        int row = idx >> 4, c = idx & 15;
        *(short8*)(&As[row * 136 + c * 8]) =
            *(const short8*)(xn + ((size_t)(a0 + row) * NSEQ + b) * DMODEL + c * 8);
    }
    __syncthreads();

    short8 af[4][4];   // [mf][kc]
    #pragma unroll
    for (int mf = 0; mf < 4; ++mf)
        #pragma unroll
        for (int kc = 0; kc < 4; ++kc)
            af[mf][kc] = *(const short8*)(
                &As[(mf * 16 + (lane & 15)) * 136 + kc * 32 + (lane >> 4) * 8]);

    f32x4 acc0[4][2], acc1[4][2];
    float smb = src_mask[b];

    auto mmat = [&](f32x4 (&acc)[4][2], short8 (&bf)[2][4]) {
        #pragma unroll
        for (int mf = 0; mf < 4; ++mf)
            #pragma unroll
            for (int nf = 0; nf < 2; ++nf)
                acc[mf][nf] = f32x4{0.f, 0.f, 0.f, 0.f};
        #pragma unroll
        for (int kc = 0; kc < 4; ++kc)
            #pragma unroll
            for (int mf = 0; mf < 4; ++mf)
                #pragma unroll
                for (int nf = 0; nf < 2; ++nf)
                    acc[mf][nf] = __builtin_amdgcn_mfma_f32_16x16x32_bf16(
                        af[mf][kc], bf[nf][kc], acc[mf][nf], 0, 0, 0);
    };
    auto epi_pair = [&](const float* b1, const float* b2, unsigned short* dst) {
        float mkv[16];
        #pragma unroll
        for (int mf = 0; mf < 4; ++mf)
            #pragma unroll
            for (int j = 0; j < 4; ++j)
                mkv[mf * 4 + j] =
                    src_mask[a0 + mf * 16 + ((lane >> 4) << 2) + j] * smb;
        #pragma unroll
        for (int nf = 0; nf < 2; ++nf) {
            int h = n0 + nf * 16 + (lane & 15);
            float b1v = b1[h], b2v = b2[h];
            #pragma unroll
            for (int mf = 0; mf < 4; ++mf) {
                int abase = a0 + mf * 16 + ((lane >> 4) << 2);
                float o_[4];
                #pragma unroll
                for (int j = 0; j < 4; ++j) {
                    float pv = acc0[mf][nf][j] + b1v;
                    float gv = acc1[mf][nf][j] + b2v;
                    o_[j] = pv * mkv[mf * 4 + j] * sigfast(gv);
                }
                uint2 pk;
                pk.x = cvt_pk_bf16(o_[0], o_[1]);
                pk.y = cvt_pk_bf16(o_[2], o_[3]);
                *(uint2*)(dst + (size_t)h * PL + (size_t)b * NSEQ + abase) = pk;
            }
        }
    };

    // order: 0=wl(acc0) 1=wlg(acc1) -> left; 2=wr 3=wrg -> right; 4=wog
    mmat(acc0, bfA);
    loadB(bfA, 2);
    mmat(acc1, bfB);
    loadB(bfB, 3);
    epi_pair(bl, blg, left_t);
    mmat(acc0, bfA);
    loadB(bfA, 4);
    mmat(acc1, bfB);
    epi_pair(br, brg, right_t);
    mmat(acc0, bfA);

    __syncthreads();
    #pragma unroll
    for (int nf = 0; nf < 2; ++nf) {
        int h = n0 + nf * 16 + (lane & 15);
        float bv = bog[h];
        #pragma unroll
        for (int mf = 0; mf < 4; ++mf) {
            int rloc = mf * 16 + ((lane >> 4) << 2);
            #pragma unroll
            for (int j = 0; j < 4; ++j)
                As[(rloc + j) * 136 + h] = f2b(sigfast(acc0[mf][nf][j] + bv));
        }
    }
    __syncthreads();
    #pragma unroll
    for (int it = 0; it < 4; ++it) {
        int idx = it * 256 + t;
        int row = idx >> 4, c = idx & 15;
        *(short8*)(og + ((size_t)(a0 + row) * NSEQ + b) * DMODEL + c * 8) =
            *(const short8*)(&As[row * 136 + c * 8]);
    }
}

// ---------------------------------------------------------------------------
// Einsum: per d-plane GEMM C[i][j] = sum_k A[i][k]*B[j][k].
// 128x128 tile, BK=32, global_load_lds width-16 staging (linear LDS, stride
// 32 shorts), double-buffered, ONE barrier/iter; loads fly under MFMAs.
// ---------------------------------------------------------------------------
__global__ __launch_bounds__(256) void k_einsum(
    const unsigned short* __restrict__ lt,
    const unsigned short* __restrict__ rt,
    unsigned short* __restrict__ mid) {
    __shared__ __align__(16) unsigned short As[2][128 * 32];
    __shared__ __align__(16) unsigned short Bs[2][128 * 32];
    const int t = threadIdx.x, lane = t & 63, wv = t >> 6;
    const int bid = blockIdx.x;
    const int xcd = bid & 7, slot = bid >> 3;
    const int d = xcd * 16 + (slot >> 4);
    const int tile = slot & 15;
    const int i0 = (tile >> 2) * 128, j0 = (tile & 3) * 128;
    const int m0 = (wv >> 1) * 64, n0 = (wv & 1) * 64;
    const unsigned short* Ag = lt + (size_t)d * PL;
    const unsigned short* Bg = rt + (size_t)d * PL;

    auto stage = [&](int buf, int k0) {
        #pragma unroll
        for (int r = 0; r < 2; ++r) {
            int c = r * 256 + wv * 64 + lane;
            int row = c >> 2, sub = c & 3;
            gload_lds16(Ag + (size_t)(i0 + row) * NSEQ + k0 + sub * 8,
                        &As[buf][(r * 256 + wv * 64) * 8]);
            gload_lds16(Bg + (size_t)(j0 + row) * NSEQ + k0 + sub * 8,
                        &Bs[buf][(r * 256 + wv * 64) * 8]);
        }
    };

    f32x4 acc[4][4];
    #pragma unroll
    for (int mf = 0; mf < 4; ++mf)
        #pragma unroll
        for (int nf = 0; nf < 4; ++nf)
            acc[mf][nf] = f32x4{0.f, 0.f, 0.f, 0.f};

    stage(0, 0);
    int cur = 0;
    const int ko = (lane >> 4) * 8;
    for (int it = 0; it < 16; ++it) {
        __syncthreads();                        // drains vmcnt -> buf[cur] ready
        if (it < 15) stage(cur ^ 1, (it + 1) * 32);  // in flight under MFMAs
        short8 af[4], bf[4];
        #pragma unroll
        for (int mf = 0; mf < 4; ++mf)
            af[mf] = *(const short8*)(&As[cur][(m0 + mf * 16 + (lane & 15)) * 32 + ko]);
        #pragma unroll
        for (int nf = 0; nf < 4; ++nf)
            bf[nf] = *(const short8*)(&Bs[cur][(n0 + nf * 16 + (lane & 15)) * 32 + ko]);
        #pragma unroll
        for (int mf = 0; mf < 4; ++mf)
            #pragma unroll
            for (int nf = 0; nf < 4; ++nf)
                acc[mf][nf] = __builtin_amdgcn_mfma_f32_16x16x32_bf16(
                    af[mf], bf[nf], acc[mf][nf], 0, 0, 0);
        cur ^= 1;
    }
    unsigned short* out = mid + (size_t)d * PL;
    #pragma unroll
    for (int mf = 0; mf < 4; ++mf) {
        int rbase = i0 + m0 + mf * 16 + ((lane >> 4) << 2);
        #pragma unroll
        for (int nf = 0; nf < 4; ++nf) {
            int col = j0 + n0 + nf * 16 + (lane & 15);
            #pragma unroll
            for (int j = 0; j < 4; ++j)
                out[(size_t)(rbase + j) * NSEQ + col] = f2b(acc[mf][nf][j]);
        }
    }
}

// ---------------------------------------------------------------------------
// Fused LN2*gate + output projection. Block = 64 positions, 256 threads.
// Phase 1: wave w reads d-slice [32w,32w+32) of mid for position p0+lane
// (coalesced 128B/wave per plane), 4-wave LDS stats reduce, normalize*og
// -> bf16 A-tile in LDS. Phase 2: GEMM (A 64x128 @ wo) -> fp32 out.
// ---------------------------------------------------------------------------
__global__ __launch_bounds__(256) void k_lnout(
    const unsigned short* __restrict__ mid,
    const unsigned short* __restrict__ og,
    const float* __restrict__ sc, const float* __restrict__ bi,
    const unsigned short* __restrict__ wt_o,
    const float* __restrict__ bo,
    float* __restrict__ out) {
    __shared__ __align__(16) unsigned short As[64 * 136];
    __shared__ __align__(16) unsigned short Bs[128 * 136];
    __shared__ float2 st[4][64];
    const int t = threadIdx.x, lane = t & 63, wv = t >> 6;
    const size_t p0 = (size_t)blockIdx.x * 64;
    const size_t p = p0 + lane;
    const int d0 = wv * 32;

    // stage Bs (wo^T) early — overlaps the strided mid reads
    #pragma unroll
    for (int it = 0; it < 8; ++it) {
        int idx = it * 256 + t;
        int h = idx >> 4, c = idx & 15;
        *(short8*)(&Bs[h * 136 + c * 8]) = *(const short8*)(wt_o + h * 128 + c * 8);
    }

    // read my 32 d-planes for position p
    unsigned short v16[32];
    float s = 0.f, sq = 0.f;
    #pragma unroll
    for (int e = 0; e < 32; ++e) {
        unsigned short u = mid[(size_t)(d0 + e) * PL + p];
        v16[e] = u;
        float f = b2f(u);
        s += f; sq += f * f;
    }
    st[wv][lane] = float2{s, sq};
    __syncthreads();
    float2 s0 = st[0][lane], s1 = st[1][lane], s2 = st[2][lane], s3 = st[3][lane];
    float S = s0.x + s1.x + s2.x + s3.x;
    float Q = s0.y + s1.y + s2.y + s3.y;
    float mean = S * (1.f / 128.f);
    float inv  = rsqrtf(Q * (1.f / 128.f) - mean * mean + 1e-6f);

    // normalize * og -> As[lane][d0..d0+31] (uint4 stores, 272B row stride)
    #pragma unroll
    for (int c = 0; c < 4; ++c) {
        short8 ov = *(const short8*)(og + p * DMODEL + d0 + c * 8);
        float y[8];
        #pragma unroll
        for (int e = 0; e < 8; ++e) {
            int dd = d0 + c * 8 + e;
            float v = b2f(v16[c * 8 + e]);
            y[e] = ((v - mean) * inv * sc[dd] + bi[dd]) * b2f((unsigned short)ov[e]);
        }
        uint4 pk;
        pk.x = cvt_pk_bf16(y[0], y[1]);
        pk.y = cvt_pk_bf16(y[2], y[3]);
        pk.z = cvt_pk_bf16(y[4], y[5]);
        pk.w = cvt_pk_bf16(y[6], y[7]);
        *(uint4*)(&As[lane * 136 + d0 + c * 8]) = pk;
    }
    __syncthreads();

    // GEMM: out[64 x 128] = As @ Bs^T(+bo), wave n-slice 32
    const int n0 = wv * 32;
    f32x4 acc[4][2];
    #pragma unroll
    for (int mf = 0; mf < 4; ++mf)
        #pragma unroll
        for (int nf = 0; nf < 2; ++nf)
            acc[mf][nf] = f32x4{0.f, 0.f, 0.f, 0.f};
    #pragma unroll
    for (int kc = 0; kc < 4; ++kc) {
        int ko = kc * 32 + (lane >> 4) * 8;
        short8 af[4], bf[2];
        #pragma unroll
        for (int mf = 0; mf < 4; ++mf)
            af[mf] = *(const short8*)(&As[(mf * 16 + (lane & 15)) * 136 + ko]);
        #pragma unroll
        for (int nf = 0; nf < 2; ++nf)
            bf[nf] = *(const short8*)(&Bs[(n0 + nf * 16 + (lane & 15)) * 136 + ko]);
        #pragma unroll
        for (int mf = 0; mf < 4; ++mf)
            #pragma unroll
            for (int nf = 0; nf < 2; ++nf)
                acc[mf][nf] = __builtin_amdgcn_mfma_f32_16x16x32_bf16(
                    af[mf], bf[nf], acc[mf][nf], 0, 0, 0);
    }
    #pragma unroll
    for (int nf = 0; nf < 2; ++nf) {
        int n = n0 + nf * 16 + (lane & 15);
        float bv = bo[n];
        #pragma unroll
        for (int mf = 0; mf < 4; ++mf) {
            int rb = mf * 16 + ((lane >> 4) << 2);
            #pragma unroll
            for (int j = 0; j < 4; ++j)
                out[(p0 + rb + j) * DMODEL + n] = acc[mf][nf][j] + bv;
        }
    }
}

// ---------------------------------------------------------------------------
extern "C" void kernel_launch(void* const* d_in, const int* in_sizes, int n_in,
                              void* d_out, int out_size, void* d_ws, size_t ws_size,
                              hipStream_t stream) {
    const float* x    = (const float*)d_in[0];
    const float* sm   = (const float*)d_in[1];
    const float* ln1s = (const float*)d_in[2];
    const float* ln1b = (const float*)d_in[3];
    const float* wl   = (const float*)d_in[4];
    const float* bl   = (const float*)d_in[5];
    const float* wr   = (const float*)d_in[6];
    const float* br   = (const float*)d_in[7];
    const float* wlg  = (const float*)d_in[8];
    const float* blg  = (const float*)d_in[9];
    const float* wrg  = (const float*)d_in[10];
    const float* brg  = (const float*)d_in[11];
    const float* wog  = (const float*)d_in[12];
    const float* bog  = (const float*)d_in[13];
    const float* ln2s = (const float*)d_in[14];
    const float* ln2b = (const float*)d_in[15];
    const float* wo   = (const float*)d_in[16];
    const float* bo   = (const float*)d_in[17];
    float* out = (float*)d_out;

    // workspace: wt | xn(64MB) | lt | rt (padded 64.06MB) | og(64MB) | mid
    char* ws = (char*)d_ws;
    const size_t SZ_XN = 67108864ull;           // 64 MB
    const size_t SZ_PL = (size_t)PL * 128 * 2;  // 67,174,400 B
    unsigned short* wt  = (unsigned short*)ws;
    unsigned short* xn  = (unsigned short*)(ws + 196608);
    unsigned short* lt  = (unsigned short*)(ws + 196608 + SZ_XN);
    unsigned short* rt  = (unsigned short*)(ws + 196608 + SZ_XN + SZ_PL);
    unsigned short* ogb = (unsigned short*)(ws + 196608 + SZ_XN + 2 * SZ_PL);
    unsigned short* mid = (unsigned short*)(ws + 196608 + 2 * SZ_XN + 2 * SZ_PL);

    k_wt_all<<<384, 256, 0, stream>>>(wl, wlg, wr, wrg, wog, wo, wt);
    k_ln1<<<32768, 256, 0, stream>>>(x, ln1s, ln1b, xn);
    k_proj<<<dim3(8, 512), 256, 0, stream>>>(xn, sm, wt,
                                             bl, blg, br, brg, bog, lt, rt, ogb);
    k_einsum<<<2048, 256, 0, stream>>>(lt, rt, mid);
    k_lnout<<<4096, 256, 0, stream>>>(mid, ogb, ln2s, ln2b,
                                      wt + 5 * 16384, bo, out);
}